// Round 3
// baseline (837.618 us; speedup 1.0000x reference)
//
#include <hip/hip_runtime.h>
#include <math.h>
#include <stdint.h>

#define B_  16
#define T_  4096
#define D_  512
#define M_  256
#define TP_ 4098   // T + 2 causal pad rows per batch (padded hidden layout)

// output element offsets (float elements, concatenated in reference return order)
static constexpr long O_RATE = 0;          // [B,1]
static constexpr long O_ZOP  = 16;         // [B,8]
static constexpr long O_RVAL = 144;        // [B,M]
static constexpr long O_RVAR = 4240;       // [B,M]
static constexpr long O_RCOV = 8336;       // [B,M]
static constexpr long O_MASK = 12432;      // [B,T]
static constexpr long O_LOGD = 77968;      // [B,T]
static constexpr long O_RESID= 143504;     // [B,T]
static constexpr long O_ATTN = 209040;     // [B,T,M]
static constexpr long O_FIT  = 16986256;   // [B,T]

typedef unsigned short u16;
typedef __attribute__((ext_vector_type(8))) __bf16 bf16x8;
typedef __attribute__((ext_vector_type(4))) float fx4;

__device__ __forceinline__ float b2f(u16 u){ union{float f;uint32_t i;}v; v.i=((uint32_t)u)<<16; return v.f; }
__device__ __forceinline__ u16 f2b(float f){ union{float f;uint32_t i;}v; v.f=f; uint32_t r=v.i+0x7fffu+((v.i>>16)&1u); return (u16)(r>>16); }
__device__ __forceinline__ float clip01(float x){ return fminf(fmaxf(x, 0.f), 1.f); }
__device__ __forceinline__ float gelu_f(float x){ return 0.5f*x*(1.0f+erff(x*0.70710678118654752440f)); }

__device__ __forceinline__ void cp16(const u16* g, u16* l){
  __builtin_amdgcn_global_load_lds((__attribute__((address_space(1))) void*)g,
                                   (__attribute__((address_space(3))) void*)l, 16, 0, 0);
}

// ---------------- init: zero pad rows of chunk buffers, S, zero_operator ----
__global__ void k_init(u16* __restrict__ h0c, u16* __restrict__ h1c, int Cloc,
                       float* __restrict__ S, float* __restrict__ out){
  int i = blockIdx.x*256 + threadIdx.x;
  int padN = Cloc << 10;                 // u16 pad elems per buffer (C x 2rows x 512)
  if (i < 2*padN){
    int buf = (i >= padN) ? 1 : 0;
    int j = i - buf*padN;
    int lb = j >> 10, o = j & 1023;
    u16* h = buf ? h1c : h0c;
    h[lb*TP_*D_ + o] = 0;
  } else {
    int k = i - 2*padN;
    if (k < 12288) S[k] = 0.f;
    else if (k < 12416) out[O_ZOP + (k - 12288)] = 0.f;
  }
}

// ---- repack conv weights [O][I][K]->bf16 [conv][tap][O][I]; role_key->bf16 -
__global__ void k_repack(const float* __restrict__ w1, const float* __restrict__ w2,
                         const float* __restrict__ rk,
                         u16* __restrict__ wrp, u16* __restrict__ rkb){
  int i = blockIdx.x*256 + threadIdx.x;       // 1572864 + 131072 total
  if (i < 1572864){
    int conv = i / 786432;
    int r = i - conv*786432;
    int tap = r / 262144;
    int r2 = r - tap*262144;
    int o = r2 >> 9, ic = r2 & 511;
    const float* w = conv ? w2 : w1;
    wrp[i] = f2b(w[(o*512 + ic)*3 + tap]);
  } else {
    int j = i - 1572864;
    rkb[j] = f2b(rk[j]);
  }
}

// ---------------- per-batch: mask/logdur outputs, lower median, residual ----
__global__ __launch_bounds__(1024) void k_median(
    const float* __restrict__ dur, const float* __restrict__ msk,
    float* __restrict__ out, float* __restrict__ supp_f, float* __restrict__ resid_f){
  __shared__ float sd[4096];
  __shared__ float sred[1024];
  __shared__ float sbc;
  const int tid = threadIdx.x;
  const int b = blockIdx.x;
  float msum = 0.f;
  for (int i = tid; i < 4096; i += 1024){
    int bt = (b << 12) + i;
    float m  = clip01(msk[bt]);
    float ld = logf(fmaxf(dur[bt], 1e-4f)) * m;
    sd[i] = (m > 0.5f) ? ld : 1e30f;
    msum += m;
    out[O_MASK + bt] = m;
    out[O_LOGD + bt] = ld;
  }
  sred[tid] = msum;
  __syncthreads();
  for (int s = 512; s > 0; s >>= 1){
    if (tid < s) sred[tid] += sred[tid + s];
    __syncthreads();
  }
  float msumT = sred[0];
  // bitonic ascending sort of sd[0..4095]
  for (int k = 2; k <= 4096; k <<= 1)
    for (int j = k >> 1; j > 0; j >>= 1){
      __syncthreads();
      #pragma unroll 1
      for (int base = 0; base < 4096; base += 1024){
        int i = base + tid;
        int ixj = i ^ j;
        if (ixj > i){
          float a = sd[i], c = sd[ixj];
          bool sw = ((i & k) == 0) ? (a > c) : (a < c);
          if (sw){ sd[i] = c; sd[ixj] = a; }
        }
      }
    }
  __syncthreads();
  if (tid == 0){
    int cnt = (int)(msumT + 0.5f);
    float med = (cnt > 0) ? sd[(cnt - 1) >> 1] : 0.f;
    out[O_RATE + b] = med;
    supp_f[b] = fmaxf(msumT, 1.0f);
    sbc = med;
  }
  __syncthreads();
  float med = sbc;
  for (int i = tid; i < 4096; i += 1024){
    int bt = (b << 12) + i;
    float m  = clip01(msk[bt]);
    float ld = logf(fmaxf(dur[bt], 1e-4f)) * m;
    float r = (ld - med) * m;
    resid_f[bt] = r;
    out[O_RESID + bt] = r;
  }
}

// ---------------- embedding + aux proj into padded bf16 chunk buffer --------
__global__ __launch_bounds__(256) void k_embed(
    const int* __restrict__ units, const float* __restrict__ dur,
    const float* __restrict__ msk, const float* __restrict__ emb,
    const float* __restrict__ pw, const float* __restrict__ pb,
    u16* __restrict__ h0c, int b0){
  int wid = threadIdx.x >> 6, lane = threadIdx.x & 63;
  int r = blockIdx.x*4 + wid;            // local row in chunk
  int lb = r >> 12, t = r & 4095;
  int bt = ((b0 + lb) << 12) + t;        // global row
  float m = clip01(msk[bt]);
  float ld = logf(fmaxf(dur[bt], 1e-4f)) * m;
  int u = units[bt];
  int c = lane*8;
  const float* er = emb + (long)u*512 + c;
  float4 e0 = *(const float4*)er;
  float4 e1 = *(const float4*)(er + 4);
  float x[8] = {e0.x,e0.y,e0.z,e0.w,e1.x,e1.y,e1.z,e1.w};
  ushort4 o0, o1; float y[8];
  #pragma unroll
  for (int j=0;j<8;++j)
    y[j] = x[j] + ld*pw[(c+j)*4] + pb[c+j];
  o0.x=f2b(y[0]); o0.y=f2b(y[1]); o0.z=f2b(y[2]); o0.w=f2b(y[3]);
  o1.x=f2b(y[4]); o1.y=f2b(y[5]); o1.z=f2b(y[6]); o1.w=f2b(y[7]);
  u16* dst = h0c + ((long)lb*TP_ + 2 + t)*D_ + c;
  *(ushort4*)dst = o0;
  *(ushort4*)(dst + 4) = o1;
}

// ---------------- causal conv (K=3) as MFMA GEMM + bias + exact GELU --------
__global__ __launch_bounds__(256) void k_conv(const u16* __restrict__ hin,
                                              const u16* __restrict__ wrp,
                                              const float* __restrict__ bias,
                                              u16* __restrict__ hout){
  __shared__ __align__(16) u16 As[128*32];
  __shared__ __align__(16) u16 Bs[128*32];
  const int tid = threadIdx.x;
  const int lane = tid & 63, wid = tid >> 6;
  const int wm = wid >> 1, wn = wid & 1;
  const int nt = blockIdx.x & 3, mt = blockIdx.x >> 2;
  const int lb = mt >> 5, t0 = (mt & 31) << 7;
  const int n0 = nt << 7;
  const long aBase = ((long)lb*TP_ + t0)*D_;

  fx4 acc[4][4];
  #pragma unroll
  for (int i=0;i<4;++i)
    #pragma unroll
    for (int j=0;j<4;++j){ acc[i][j][0]=0.f; acc[i][j][1]=0.f; acc[i][j][2]=0.f; acc[i][j][3]=0.f; }

  for (int kt = 0; kt < 48; ++kt){
    const int tap = kt >> 4;
    const int kc = (kt & 15) << 5;
    #pragma unroll
    for (int q = 0; q < 2; ++q){
      int s = q*256 + tid;
      int g = s >> 7, row = s & 127;
      cp16(hin + aBase + (row + tap)*D_ + kc + g*8, &As[(s & ~63)*8]);
    }
    #pragma unroll
    for (int q = 0; q < 2; ++q){
      int s = q*256 + tid;
      int g = s >> 7, row = s & 127;
      cp16(wrp + ((long)tap*D_ + n0 + row)*D_ + kc + g*8, &Bs[(s & ~63)*8]);
    }
    __syncthreads();
    bf16x8 af[4], bf[4];
    const int g4 = lane >> 4, r16 = lane & 15;
    #pragma unroll
    for (int mi=0;mi<4;++mi)
      af[mi] = *(const bf16x8*)&As[(g4*128 + wm*64 + mi*16 + r16)*8];
    #pragma unroll
    for (int ni=0;ni<4;++ni)
      bf[ni] = *(const bf16x8*)&Bs[(g4*128 + wn*64 + ni*16 + r16)*8];
    #pragma unroll
    for (int mi=0;mi<4;++mi)
      #pragma unroll
      for (int ni=0;ni<4;++ni)
        acc[mi][ni] = __builtin_amdgcn_mfma_f32_16x16x32_bf16(af[mi], bf[ni], acc[mi][ni], 0,0,0);
    __syncthreads();
  }
  const int g4 = lane >> 4, cl = lane & 15;
  float bv[4];
  #pragma unroll
  for (int ni=0;ni<4;++ni) bv[ni] = bias[n0 + wn*64 + ni*16 + cl];
  #pragma unroll
  for (int mi=0;mi<4;++mi)
    #pragma unroll
    for (int ni=0;ni<4;++ni)
      #pragma unroll
      for (int rg=0;rg<4;++rg){
        int row = wm*64 + mi*16 + g4*4 + rg;
        float v = gelu_f(acc[mi][ni][rg] + bv[ni]);
        hout[((long)lb*TP_ + 2 + t0 + row)*D_ + n0 + wn*64 + ni*16 + cl] = f2b(v);
      }
}

// ---------------- layernorm * mask, in-place on padded bf16 chunk buffer ----
__global__ __launch_bounds__(256) void k_ln(u16* __restrict__ h,
                                            const float* __restrict__ g_,
                                            const float* __restrict__ be,
                                            const float* __restrict__ msk, int b0){
  int wid = threadIdx.x >> 6, lane = threadIdx.x & 63;
  int r = blockIdx.x*4 + wid;
  int lb = r >> 12, t = r & 4095;
  int gbt = ((b0 + lb) << 12) + t;
  u16* src = h + ((long)lb*TP_ + 2 + t)*D_ + lane*8;
  ushort4 v0 = *(const ushort4*)src;
  ushort4 v1 = *(const ushort4*)(src + 4);
  float x[8] = {b2f(v0.x),b2f(v0.y),b2f(v0.z),b2f(v0.w),
                b2f(v1.x),b2f(v1.y),b2f(v1.z),b2f(v1.w)};
  float s = 0.f;
  #pragma unroll
  for (int j=0;j<8;++j) s += x[j];
  #pragma unroll
  for (int d=1; d<64; d<<=1) s += __shfl_xor(s, d);
  float mu = s * (1.f/512.f);
  float q = 0.f;
  #pragma unroll
  for (int j=0;j<8;++j){ float dd = x[j]-mu; q += dd*dd; }
  #pragma unroll
  for (int d=1; d<64; d<<=1) q += __shfl_xor(q, d);
  float inv = rsqrtf(q * (1.f/512.f) + 1e-5f);
  float mk = clip01(msk[gbt]);
  int c = lane*8;
  ushort4 o0, o1; float y[8];
  #pragma unroll
  for (int j=0;j<8;++j)
    y[j] = ((x[j]-mu)*inv*g_[c+j] + be[c+j]) * mk;
  o0.x=f2b(y[0]); o0.y=f2b(y[1]); o0.z=f2b(y[2]); o0.w=f2b(y[3]);
  o1.x=f2b(y[4]); o1.y=f2b(y[5]); o1.z=f2b(y[6]); o1.w=f2b(y[7]);
  *(ushort4*)src = o0;
  *(ushort4*)(src + 4) = o1;
}

// ---------------- score GEMM + fused softmax -> attn (float out) ------------
__global__ __launch_bounds__(256) void k_score(const u16* __restrict__ h,
                                               const u16* __restrict__ rkb,
                                               const float* __restrict__ msk,
                                               float* __restrict__ out, int b0){
  __shared__ __align__(16) u16 As[128*32];
  __shared__ __align__(16) u16 Bs[256*32];
  __shared__ float smax[128][2];
  __shared__ float ssum[128][2];
  const int tid = threadIdx.x;
  const int lane = tid & 63, wid = tid >> 6;
  const int wm = wid >> 1, wn = wid & 1;
  const int r0 = blockIdx.x << 7;           // local row base in chunk
  const int lb = r0 >> 12, t0 = r0 & 4095;
  const long gRow0 = (long)((b0 + lb) << 12) + t0; // global row base
  const long aBase = ((long)lb*TP_ + 2 + t0)*D_;

  fx4 acc[4][8];
  #pragma unroll
  for (int i=0;i<4;++i)
    #pragma unroll
    for (int j=0;j<8;++j){ acc[i][j][0]=0.f; acc[i][j][1]=0.f; acc[i][j][2]=0.f; acc[i][j][3]=0.f; }

  for (int kt = 0; kt < 16; ++kt){
    const int kc = kt << 5;
    #pragma unroll
    for (int q = 0; q < 2; ++q){
      int s = q*256 + tid;
      int g = s >> 7, row = s & 127;
      cp16(h + aBase + row*D_ + kc + g*8, &As[(s & ~63)*8]);
    }
    #pragma unroll
    for (int q = 0; q < 4; ++q){
      int s = q*256 + tid;
      int g = s >> 8, row = s & 255;
      cp16(rkb + row*D_ + kc + g*8, &Bs[(s & ~63)*8]);
    }
    __syncthreads();
    bf16x8 af[4], bf[8];
    const int g4 = lane >> 4, r16 = lane & 15;
    #pragma unroll
    for (int mi=0;mi<4;++mi)
      af[mi] = *(const bf16x8*)&As[(g4*128 + wm*64 + mi*16 + r16)*8];
    #pragma unroll
    for (int ni=0;ni<8;++ni)
      bf[ni] = *(const bf16x8*)&Bs[(g4*256 + wn*128 + ni*16 + r16)*8];
    #pragma unroll
    for (int mi=0;mi<4;++mi)
      #pragma unroll
      for (int ni=0;ni<8;++ni)
        acc[mi][ni] = __builtin_amdgcn_mfma_f32_16x16x32_bf16(af[mi], bf[ni], acc[mi][ni], 0,0,0);
    __syncthreads();
  }
  const float SCALE = 0.044194173824159216f;   // 1/sqrt(512)
  const int g4 = lane >> 4, cl = lane & 15;
  float gmx[4][4];
  #pragma unroll
  for (int mi=0;mi<4;++mi)
    #pragma unroll
    for (int rg=0;rg<4;++rg){
      float mx = -1e30f;
      #pragma unroll
      for (int ni=0;ni<8;++ni){
        acc[mi][ni][rg] *= SCALE;
        mx = fmaxf(mx, acc[mi][ni][rg]);
      }
      #pragma unroll
      for (int d=1; d<16; d<<=1) mx = fmaxf(mx, __shfl_xor(mx, d));
      if (cl == 0) smax[wm*64 + mi*16 + g4*4 + rg][wn] = mx;
    }
  __syncthreads();
  #pragma unroll
  for (int mi=0;mi<4;++mi)
    #pragma unroll
    for (int rg=0;rg<4;++rg){
      int row = wm*64 + mi*16 + g4*4 + rg;
      gmx[mi][rg] = fmaxf(smax[row][0], smax[row][1]);
    }
  #pragma unroll
  for (int mi=0;mi<4;++mi)
    #pragma unroll
    for (int rg=0;rg<4;++rg){
      float s = 0.f;
      #pragma unroll
      for (int ni=0;ni<8;++ni){
        float e = expf(acc[mi][ni][rg] - gmx[mi][rg]);
        acc[mi][ni][rg] = e;
        s += e;
      }
      #pragma unroll
      for (int d=1; d<16; d<<=1) s += __shfl_xor(s, d);
      if (cl == 0) ssum[wm*64 + mi*16 + g4*4 + rg][wn] = s;
    }
  __syncthreads();
  #pragma unroll
  for (int mi=0;mi<4;++mi)
    #pragma unroll
    for (int rg=0;rg<4;++rg){
      int row = wm*64 + mi*16 + g4*4 + rg;
      float tot = ssum[row][0] + ssum[row][1];
      float mk = clip01(msk[gRow0 + row]);
      float f = mk / tot;
      #pragma unroll
      for (int ni=0;ni<8;++ni)
        out[O_ATTN + (gRow0 + row)*M_ + wn*128 + ni*16 + cl] = acc[mi][ni][rg] * f;
    }
}

// ---------------- column reductions over T: S0/S1/S2 ------------------------
__global__ __launch_bounds__(256) void k_reduce(const float* __restrict__ attn,
                                                const float* __restrict__ resid,
                                                float* __restrict__ S0,
                                                float* __restrict__ S1,
                                                float* __restrict__ S2){
  int b = blockIdx.y, tc = blockIdx.x, m = threadIdx.x;
  float s0=0.f, s1=0.f, s2=0.f;
  int tbase = tc*256;
  const float* ap = attn + (long)(b*T_ + tbase)*M_ + m;
  const float* rp = resid + b*T_ + tbase;
  #pragma unroll 4
  for (int i=0;i<256;++i){
    float a = ap[(long)i*M_];
    float r = rp[i];
    s0 += a; s1 += a*r; s2 += a*r*r;
  }
  atomicAdd(&S0[b*M_ + m], s0);
  atomicAdd(&S1[b*M_ + m], s1);
  atomicAdd(&S2[b*M_ + m], s2);
}

// ---------------- finalize role_value / role_var / role_cov -----------------
__global__ __launch_bounds__(256) void k_final(const float* __restrict__ S0,
                                               const float* __restrict__ S1,
                                               const float* __restrict__ S2,
                                               const float* __restrict__ supp,
                                               float* __restrict__ out,
                                               float* __restrict__ rvf){
  int i = blockIdx.x*256 + threadIdx.x;   // 4096
  int b = i >> 8;
  float s0 = S0[i], s1 = S1[i], s2 = S2[i];
  float cov = fmaxf(s0, 1e-6f);
  float rv = s1 / cov;
  float var = fmaxf((s2 - 2.f*rv*s1 + rv*rv*s0) / cov, 1e-4f);
  float rc = fmaxf(cov / supp[b], 0.05f);
  out[O_RVAL + i] = rv;
  out[O_RVAR + i] = var;
  out[O_RCOV + i] = rc;
  rvf[i] = rv;
}

// ---------------- prompt_role_fit = (attn . role_value) * mask --------------
__global__ __launch_bounds__(256) void k_fit(const float* __restrict__ attn,
                                             const float* __restrict__ rvf,
                                             const float* __restrict__ msk,
                                             float* __restrict__ out){
  int wid = threadIdx.x >> 6, lane = threadIdx.x & 63;
  int row = blockIdx.x*4 + wid;
  int b = row >> 12;
  float4 a = *(const float4*)(attn + (long)row*M_ + lane*4);
  float4 r = *(const float4*)(rvf + b*M_ + lane*4);
  float dot = a.x*r.x + a.y*r.y + a.z*r.z + a.w*r.w;
  #pragma unroll
  for (int d=1; d<64; d<<=1) dot += __shfl_xor(dot, d);
  if (lane == 0) out[O_FIT + row] = dot * clip01(msk[row]);
}

// ---------------- launcher --------------------------------------------------
extern "C" void kernel_launch(void* const* d_in, const int* in_sizes, int n_in,
                              void* d_out, int out_size, void* d_ws, size_t ws_size,
                              hipStream_t stream) {
  const int*   units = (const int*)d_in[0];
  const float* dur   = (const float*)d_in[1];
  const float* msk   = (const float*)d_in[2];
  const float* emb   = (const float*)d_in[3];
  const float* pw    = (const float*)d_in[4];
  const float* pb    = (const float*)d_in[5];
  const float* w1    = (const float*)d_in[6];
  const float* b1    = (const float*)d_in[7];
  const float* w2    = (const float*)d_in[8];
  const float* b2c   = (const float*)d_in[9];
  const float* lng   = (const float*)d_in[10];
  const float* lnb   = (const float*)d_in[11];
  const float* rk    = (const float*)d_in[12];
  float* out = (float*)d_out;
  char* ws = (char*)d_ws;

  // pick the largest batch-chunk C whose workspace fits ws_size
  const size_t chunkB = (size_t)TP_*D_*2;              // per-batch padded bf16 bytes
  const size_t tail = 3145728 + 262144 + 262144 + 49152 + 64 + 16384;
  int C = 16;
  while (C > 1 && (2*(size_t)C*chunkB + tail) > ws_size) C >>= 1;
  const int nch = 16 / C;
  const size_t hB = (size_t)C*chunkB;

  u16*   h0c     = (u16*)(ws);
  u16*   h1c     = (u16*)(ws + hB);
  u16*   wrp     = (u16*)(ws + 2*hB);                          // 3,145,728 B
  u16*   rkb     = (u16*)(ws + 2*hB + 3145728);                // 262,144 B
  float* resid_f = (float*)(ws + 2*hB + 3145728 + 262144);     // 262,144 B
  float* S0      = (float*)(ws + 2*hB + 3145728 + 262144 + 262144);
  float* S1      = S0 + 4096;
  float* S2      = S1 + 4096;
  float* supp_f  = S2 + 4096;
  float* rv_f    = supp_f + 16;

  int initN = 2*(C << 10) + 12288 + 128;
  k_init  <<<(initN + 255)/256, 256, 0, stream>>>(h0c, h1c, C, S0, out);
  k_repack<<<6656, 256, 0, stream>>>(w1, w2, rk, wrp, rkb);
  k_median<<<16,  1024, 0, stream>>>(dur, msk, out, supp_f, resid_f);
  for (int c = 0; c < nch; ++c){
    int b0 = c*C;
    k_embed<<<C*1024, 256, 0, stream>>>(units, dur, msk, emb, pw, pb, h0c, b0);
    k_conv <<<C*128,  256, 0, stream>>>(h0c, wrp,          b1,  h1c);
    k_conv <<<C*128,  256, 0, stream>>>(h1c, wrp + 786432, b2c, h0c);
    k_ln   <<<C*1024, 256, 0, stream>>>(h0c, lng, lnb, msk, b0);
    k_score<<<C*32,   256, 0, stream>>>(h0c, rkb, msk, out, b0);
  }
  k_reduce<<<dim3(16,16), 256, 0, stream>>>(out + O_ATTN, resid_f, S0, S1, S2);
  k_final <<<16,    256, 0, stream>>>(S0, S1, S2, supp_f, out, rv_f);
  k_fit   <<<16384, 256, 0, stream>>>(out + O_ATTN, rv_f, msk, out);
}

// Round 4
// 680.210 us; speedup vs baseline: 1.2314x; 1.2314x over previous
//
#include <hip/hip_runtime.h>
#include <math.h>
#include <stdint.h>

#define B_  16
#define T_  4096
#define D_  512
#define M_  256
#define TP_ 4098   // T + 2 causal pad rows per batch (padded hidden layout)

// output element offsets (float elements, concatenated in reference return order)
static constexpr long O_RATE = 0;          // [B,1]
static constexpr long O_ZOP  = 16;         // [B,8]
static constexpr long O_RVAL = 144;        // [B,M]
static constexpr long O_RVAR = 4240;       // [B,M]
static constexpr long O_RCOV = 8336;       // [B,M]
static constexpr long O_MASK = 12432;      // [B,T]
static constexpr long O_LOGD = 77968;      // [B,T]
static constexpr long O_RESID= 143504;     // [B,T]
static constexpr long O_ATTN = 209040;     // [B,T,M]
static constexpr long O_FIT  = 16986256;   // [B,T]

typedef unsigned short u16;
typedef unsigned int u32;
typedef __attribute__((ext_vector_type(8))) __bf16 bf16x8;
typedef __attribute__((ext_vector_type(4))) float fx4;

__device__ __forceinline__ float b2f(u16 u){ union{float f;uint32_t i;}v; v.i=((uint32_t)u)<<16; return v.f; }
__device__ __forceinline__ u16 f2b(float f){ union{float f;uint32_t i;}v; v.f=f; uint32_t r=v.i+0x7fffu+((v.i>>16)&1u); return (u16)(r>>16); }
__device__ __forceinline__ float clip01(float x){ return fminf(fmaxf(x, 0.f), 1.f); }
__device__ __forceinline__ float gelu_f(float x){ return 0.5f*x*(1.0f+erff(x*0.70710678118654752440f)); }

__device__ __forceinline__ void cp16(const u16* g, u16* l){
  __builtin_amdgcn_global_load_lds((__attribute__((address_space(1))) void*)g,
                                   (__attribute__((address_space(3))) void*)l, 16, 0, 0);
}

// ---------------- init: zero pad rows of chunk buffers, S, zero_operator ----
__global__ void k_init(u16* __restrict__ h0c, u16* __restrict__ h1c, int Cloc,
                       float* __restrict__ S, float* __restrict__ out){
  int i = blockIdx.x*256 + threadIdx.x;
  int padN = Cloc << 10;                 // u16 pad elems per buffer (C x 2rows x 512)
  if (i < 2*padN){
    int buf = (i >= padN) ? 1 : 0;
    int j = i - buf*padN;
    int lb = j >> 10, o = j & 1023;
    u16* h = buf ? h1c : h0c;
    h[lb*TP_*D_ + o] = 0;
  } else {
    int k = i - 2*padN;
    if (k < 12288) S[k] = 0.f;
    else if (k < 12416) out[O_ZOP + (k - 12288)] = 0.f;
  }
}

// ---- repack conv weights [O][I][K]->bf16 [conv][tap][O][I]; role_key->bf16 -
__global__ void k_repack(const float* __restrict__ w1, const float* __restrict__ w2,
                         const float* __restrict__ rk,
                         u16* __restrict__ wrp, u16* __restrict__ rkb){
  int i = blockIdx.x*256 + threadIdx.x;       // 1572864 + 131072 total
  if (i < 1572864){
    int conv = i / 786432;
    int r = i - conv*786432;
    int tap = r / 262144;
    int r2 = r - tap*262144;
    int o = r2 >> 9, ic = r2 & 511;
    const float* w = conv ? w2 : w1;
    wrp[i] = f2b(w[(o*512 + ic)*3 + tap]);
  } else {
    int j = i - 1572864;
    rkb[j] = f2b(rk[j]);
  }
}

// ---------------- per-batch: mask/logdur outputs, exact lower median --------
// radix-select over order-flipped f32 bits; bit-exact element selection
__global__ __launch_bounds__(1024) void k_median(
    const float* __restrict__ dur, const float* __restrict__ msk,
    float* __restrict__ out, float* __restrict__ supp_f, float* __restrict__ resid_f){
  __shared__ u32 keys[4096];
  __shared__ u32 hist[2048];
  __shared__ float sred[1024];
  __shared__ u32 selBin, selRank;
  __shared__ float sMed;
  const int tid = threadIdx.x;
  const int b = blockIdx.x;
  float msum = 0.f;
  for (int i = tid; i < 4096; i += 1024){
    int bt = (b << 12) + i;
    float m  = clip01(msk[bt]);
    float ld = logf(fmaxf(dur[bt], 1e-4f)) * m;
    out[O_MASK + bt] = m;
    out[O_LOGD + bt] = ld;
    u32 u = __float_as_uint(ld);
    u32 k = (u & 0x80000000u) ? ~u : (u | 0x80000000u);
    keys[i] = (m > 0.5f) ? k : 0xFFFFFFFFu;
    msum += m;
  }
  sred[tid] = msum;
  __syncthreads();
  for (int s = 512; s > 0; s >>= 1){
    if (tid < s) sred[tid] += sred[tid + s];
    __syncthreads();
  }
  float msumT = sred[0];
  int cnt = (int)(msumT + 0.5f);
  u32 prefix = 0;
  u32 r = (cnt > 0) ? (u32)((cnt - 1) >> 1) : 0u;
  if (cnt > 0){
    #pragma unroll
    for (int p = 0; p < 3; ++p){
      const int shift = (p==0) ? 21 : (p==1) ? 10 : 0;
      const int nb = (p==2) ? 1024 : 2048;
      const u32 himask = (p==0) ? 0u : (0xFFFFFFFFu << (shift + ((p==2)?10:11)));
      hist[tid] = 0u; hist[tid + 1024] = 0u;
      __syncthreads();
      for (int i = tid; i < 4096; i += 1024){
        u32 k = keys[i];
        if ((k & himask) == prefix)
          atomicAdd(&hist[(k >> shift) & (u32)(nb-1)], 1u);
      }
      __syncthreads();
      if (tid < 64){
        u32 lane = tid;
        u32 cum = 0;
        for (int chunk = 0; chunk < nb/64; ++chunk){
          u32 v = hist[chunk*64 + lane];
          u32 incl = v;
          #pragma unroll
          for (int d = 1; d < 64; d <<= 1){
            u32 o = __shfl_up(incl, d);
            if (lane >= (u32)d) incl += o;
          }
          u32 total = __shfl(incl, 63);
          if (r < cum + total){
            u32 excl = incl - v;
            bool hit = (r >= cum + excl) && (r < cum + excl + v);
            unsigned long long bal = __ballot(hit);
            int L = __ffsll((unsigned long long)bal) - 1;
            u32 exclL = __shfl(excl, L);
            if (lane == 0){ selBin = (u32)(chunk*64 + L); selRank = r - (cum + exclL); }
            break;
          }
          cum += total;
        }
      }
      __syncthreads();
      prefix |= (selBin << shift);
      r = selRank;
      __syncthreads();
    }
  }
  if (tid == 0){
    float med = 0.f;
    if (cnt > 0){
      u32 k = prefix;
      u32 u = (k & 0x80000000u) ? (k ^ 0x80000000u) : ~k;
      med = __uint_as_float(u);
    }
    out[O_RATE + b] = med;
    supp_f[b] = fmaxf(msumT, 1.0f);
    sMed = med;
  }
  __syncthreads();
  float med = sMed;
  for (int i = tid; i < 4096; i += 1024){
    int bt = (b << 12) + i;
    float m  = clip01(msk[bt]);
    float ld = logf(fmaxf(dur[bt], 1e-4f)) * m;
    float rr = (ld - med) * m;
    resid_f[bt] = rr;
    out[O_RESID + bt] = rr;
  }
}

// ---------------- embedding + aux proj into padded bf16 chunk buffer --------
__global__ __launch_bounds__(256) void k_embed(
    const int* __restrict__ units, const float* __restrict__ dur,
    const float* __restrict__ msk, const float* __restrict__ emb,
    const float* __restrict__ pw, const float* __restrict__ pb,
    u16* __restrict__ h0c, int b0){
  int wid = threadIdx.x >> 6, lane = threadIdx.x & 63;
  int r = blockIdx.x*4 + wid;            // local row in chunk
  int lb = r >> 12, t = r & 4095;
  int bt = ((b0 + lb) << 12) + t;        // global row
  float m = clip01(msk[bt]);
  float ld = logf(fmaxf(dur[bt], 1e-4f)) * m;
  int u = units[bt];
  int c = lane*8;
  const float* er = emb + (long)u*512 + c;
  float4 e0 = *(const float4*)er;
  float4 e1 = *(const float4*)(er + 4);
  float x[8] = {e0.x,e0.y,e0.z,e0.w,e1.x,e1.y,e1.z,e1.w};
  ushort4 o0, o1; float y[8];
  #pragma unroll
  for (int j=0;j<8;++j)
    y[j] = x[j] + ld*pw[(c+j)*4] + pb[c+j];
  o0.x=f2b(y[0]); o0.y=f2b(y[1]); o0.z=f2b(y[2]); o0.w=f2b(y[3]);
  o1.x=f2b(y[4]); o1.y=f2b(y[5]); o1.z=f2b(y[6]); o1.w=f2b(y[7]);
  u16* dst = h0c + ((long)lb*TP_ + 2 + t)*D_ + c;
  *(ushort4*)dst = o0;
  *(ushort4*)(dst + 4) = o1;
}

// ---------------- causal conv (K=3) MFMA GEMM, tap-shared A, Ntile=256 ------
// A LDS: granule-major [g(4)][row(136)]; B LDS: [tap(3)][g(4)][row(256)]
__global__ __launch_bounds__(256, 2) void k_conv(const u16* __restrict__ hin,
                                                 const u16* __restrict__ wrp_c,
                                                 const float* __restrict__ bias,
                                                 u16* __restrict__ hout){
  __shared__ __align__(16) u16 smem[28928];     // 544 A-granules + 3072 B-granules
  const int tid = threadIdx.x;
  const int lane = tid & 63, wid = tid >> 6;
  const int wm = wid >> 1, wn = wid & 1;
  const int nt = blockIdx.x & 1, mt = blockIdx.x >> 1;
  const int lb = mt >> 5, t0 = (mt & 31) << 7;
  const int n0 = nt << 8;
  const long aBase = ((long)lb*TP_ + t0)*D_;
  const int maxRow = (TP_ - 1) - t0;            // clamp for A halo over-read
  const int g4 = lane >> 4, r16 = lane & 15;

  fx4 acc[4][8];
  #pragma unroll
  for (int i=0;i<4;++i)
    #pragma unroll
    for (int j=0;j<8;++j){ acc[i][j][0]=0.f; acc[i][j][1]=0.f; acc[i][j][2]=0.f; acc[i][j][3]=0.f; }

  for (int kt = 0; kt < 16; ++kt){
    const int kc = kt << 5;
    // stage A: rows t0..t0+135 (130 used), 4 col-granules, granule-major
    #pragma unroll
    for (int q = 0; q < 3; ++q){
      int s = q*256 + tid;
      if (s < 544){
        int g = s / 136, row = s - g*136;
        int rowc = min(row, maxRow);
        cp16(hin + aBase + (long)rowc*D_ + kc + g*8, &smem[s*8]);
      }
    }
    // stage B: 3 taps x 256 out-ch x 4 granules
    #pragma unroll
    for (int q = 0; q < 12; ++q){
      int s2 = q*256 + tid;
      int tap = s2 >> 10, g = (s2 >> 8) & 3, row = s2 & 255;
      cp16(wrp_c + ((long)(tap*512 + n0 + row))*512 + kc + g*8, &smem[(544 + s2)*8]);
    }
    __syncthreads();
    #pragma unroll
    for (int tap = 0; tap < 3; ++tap){
      bf16x8 af[4], bf[8];
      #pragma unroll
      for (int mi=0;mi<4;++mi)
        af[mi] = *(const bf16x8*)&smem[(g4*136 + wm*64 + mi*16 + r16 + tap)*8];
      #pragma unroll
      for (int ni=0;ni<8;++ni)
        bf[ni] = *(const bf16x8*)&smem[(544 + tap*1024 + g4*256 + wn*128 + ni*16 + r16)*8];
      #pragma unroll
      for (int mi=0;mi<4;++mi)
        #pragma unroll
        for (int ni=0;ni<8;++ni)
          acc[mi][ni] = __builtin_amdgcn_mfma_f32_16x16x32_bf16(af[mi], bf[ni], acc[mi][ni], 0,0,0);
    }
    __syncthreads();
  }
  // epilogue: bias + gelu -> LDS (64x256 u16) -> coalesced uint4 stores
  const int cl = lane & 15;
  float bv[8];
  #pragma unroll
  for (int ni=0;ni<8;++ni) bv[ni] = bias[n0 + wn*128 + ni*16 + cl];
  #pragma unroll
  for (int h = 0; h < 2; ++h){
    if (wm == h){
      #pragma unroll
      for (int mi=0;mi<4;++mi)
        #pragma unroll
        for (int ni=0;ni<8;++ni)
          #pragma unroll
          for (int rg=0;rg<4;++rg){
            int lr = mi*16 + g4*4 + rg;   // 0..63
            smem[lr*256 + wn*128 + ni*16 + cl] = f2b(gelu_f(acc[mi][ni][rg] + bv[ni]));
          }
    }
    __syncthreads();
    #pragma unroll
    for (int it = 0; it < 8; ++it){
      int c = it*256 + tid;               // 2048 chunks of 8 u16
      int rr = c >> 5, sub = c & 31;
      long grow = (long)lb*TP_ + 2 + t0 + h*64 + rr;
      *(uint4*)(hout + grow*D_ + n0 + sub*8) = *(const uint4*)(smem + c*8);
    }
    __syncthreads();
  }
}

// ---------------- layernorm * mask, in-place on padded bf16 chunk buffer ----
__global__ __launch_bounds__(256) void k_ln(u16* __restrict__ h,
                                            const float* __restrict__ g_,
                                            const float* __restrict__ be,
                                            const float* __restrict__ msk, int b0){
  int wid = threadIdx.x >> 6, lane = threadIdx.x & 63;
  int r = blockIdx.x*4 + wid;
  int lb = r >> 12, t = r & 4095;
  int gbt = ((b0 + lb) << 12) + t;
  u16* src = h + ((long)lb*TP_ + 2 + t)*D_ + lane*8;
  ushort4 v0 = *(const ushort4*)src;
  ushort4 v1 = *(const ushort4*)(src + 4);
  float x[8] = {b2f(v0.x),b2f(v0.y),b2f(v0.z),b2f(v0.w),
                b2f(v1.x),b2f(v1.y),b2f(v1.z),b2f(v1.w)};
  float s = 0.f;
  #pragma unroll
  for (int j=0;j<8;++j) s += x[j];
  #pragma unroll
  for (int d=1; d<64; d<<=1) s += __shfl_xor(s, d);
  float mu = s * (1.f/512.f);
  float q = 0.f;
  #pragma unroll
  for (int j=0;j<8;++j){ float dd = x[j]-mu; q += dd*dd; }
  #pragma unroll
  for (int d=1; d<64; d<<=1) q += __shfl_xor(q, d);
  float inv = rsqrtf(q * (1.f/512.f) + 1e-5f);
  float mk = clip01(msk[gbt]);
  int c = lane*8;
  ushort4 o0, o1; float y[8];
  #pragma unroll
  for (int j=0;j<8;++j)
    y[j] = ((x[j]-mu)*inv*g_[c+j] + be[c+j]) * mk;
  o0.x=f2b(y[0]); o0.y=f2b(y[1]); o0.z=f2b(y[2]); o0.w=f2b(y[3]);
  o1.x=f2b(y[4]); o1.y=f2b(y[5]); o1.z=f2b(y[6]); o1.w=f2b(y[7]);
  *(ushort4*)src = o0;
  *(ushort4*)(src + 4) = o1;
}

// -------- score GEMM + fused softmax -> attn (float) + fused S-reductions ---
__global__ __launch_bounds__(256, 2) void k_score(const u16* __restrict__ h,
                                                  const u16* __restrict__ rkb,
                                                  const float* __restrict__ msk,
                                                  const float* __restrict__ resid_f,
                                                  float* __restrict__ S0,
                                                  float* __restrict__ S1,
                                                  float* __restrict__ S2,
                                                  float* __restrict__ out, int b0){
  __shared__ __align__(16) u16 As[128*32];
  __shared__ __align__(16) u16 Bs[256*32];
  __shared__ float smax[128][2];
  __shared__ float ssum[128][2];
  const int tid = threadIdx.x;
  const int lane = tid & 63, wid = tid >> 6;
  const int wm = wid >> 1, wn = wid & 1;
  const int r0 = blockIdx.x << 7;           // local row base in chunk
  const int lb = r0 >> 12, t0 = r0 & 4095;
  const int gb = b0 + lb;
  const long gRow0 = ((long)gb << 12) + t0; // global row base
  const long aBase = ((long)lb*TP_ + 2 + t0)*D_;

  fx4 acc[4][8];
  #pragma unroll
  for (int i=0;i<4;++i)
    #pragma unroll
    for (int j=0;j<8;++j){ acc[i][j][0]=0.f; acc[i][j][1]=0.f; acc[i][j][2]=0.f; acc[i][j][3]=0.f; }

  for (int kt = 0; kt < 16; ++kt){
    const int kc = kt << 5;
    #pragma unroll
    for (int q = 0; q < 2; ++q){
      int s = q*256 + tid;
      int g = s >> 7, row = s & 127;
      cp16(h + aBase + row*D_ + kc + g*8, &As[(s & ~63)*8]);
    }
    #pragma unroll
    for (int q = 0; q < 4; ++q){
      int s = q*256 + tid;
      int g = s >> 8, row = s & 255;
      cp16(rkb + row*D_ + kc + g*8, &Bs[(s & ~63)*8]);
    }
    __syncthreads();
    bf16x8 af[4], bf[8];
    const int g4 = lane >> 4, r16 = lane & 15;
    #pragma unroll
    for (int mi=0;mi<4;++mi)
      af[mi] = *(const bf16x8*)&As[(g4*128 + wm*64 + mi*16 + r16)*8];
    #pragma unroll
    for (int ni=0;ni<8;++ni)
      bf[ni] = *(const bf16x8*)&Bs[(g4*256 + wn*128 + ni*16 + r16)*8];
    #pragma unroll
    for (int mi=0;mi<4;++mi)
      #pragma unroll
      for (int ni=0;ni<8;++ni)
        acc[mi][ni] = __builtin_amdgcn_mfma_f32_16x16x32_bf16(af[mi], bf[ni], acc[mi][ni], 0,0,0);
    __syncthreads();
  }
  const float SCALE = 0.044194173824159216f;   // 1/sqrt(512)
  const int g4 = lane >> 4, cl = lane & 15;
  float gmx[4][4];
  #pragma unroll
  for (int mi=0;mi<4;++mi)
    #pragma unroll
    for (int rg=0;rg<4;++rg){
      float mx = -1e30f;
      #pragma unroll
      for (int ni=0;ni<8;++ni){
        acc[mi][ni][rg] *= SCALE;
        mx = fmaxf(mx, acc[mi][ni][rg]);
      }
      #pragma unroll
      for (int d=1; d<16; d<<=1) mx = fmaxf(mx, __shfl_xor(mx, d));
      if (cl == 0) smax[wm*64 + mi*16 + g4*4 + rg][wn] = mx;
    }
  __syncthreads();
  #pragma unroll
  for (int mi=0;mi<4;++mi)
    #pragma unroll
    for (int rg=0;rg<4;++rg){
      int row = wm*64 + mi*16 + g4*4 + rg;
      gmx[mi][rg] = fmaxf(smax[row][0], smax[row][1]);
    }
  #pragma unroll
  for (int mi=0;mi<4;++mi)
    #pragma unroll
    for (int rg=0;rg<4;++rg){
      float s = 0.f;
      #pragma unroll
      for (int ni=0;ni<8;++ni){
        float e = expf(acc[mi][ni][rg] - gmx[mi][rg]);
        acc[mi][ni][rg] = e;
        s += e;
      }
      #pragma unroll
      for (int d=1; d<16; d<<=1) s += __shfl_xor(s, d);
      if (cl == 0) ssum[wm*64 + mi*16 + g4*4 + rg][wn] = s;
    }
  __syncthreads();
  float ps0[8], ps1[8], ps2[8];
  #pragma unroll
  for (int ni=0;ni<8;++ni){ ps0[ni]=0.f; ps1[ni]=0.f; ps2[ni]=0.f; }
  #pragma unroll
  for (int mi=0;mi<4;++mi)
    #pragma unroll
    for (int rg=0;rg<4;++rg){
      int row = wm*64 + mi*16 + g4*4 + rg;
      float tot = ssum[row][0] + ssum[row][1];
      float mk = clip01(msk[gRow0 + row]);
      float f = mk / tot;
      float rr = resid_f[gRow0 + row];
      #pragma unroll
      for (int ni=0;ni<8;++ni){
        float a = acc[mi][ni][rg] * f;
        out[O_ATTN + (gRow0 + row)*M_ + wn*128 + ni*16 + cl] = a;
        ps0[ni] += a; ps1[ni] += a*rr; ps2[ni] += a*rr*rr;
      }
    }
  #pragma unroll
  for (int ni=0;ni<8;++ni){
    ps0[ni] += __shfl_xor(ps0[ni], 16); ps0[ni] += __shfl_xor(ps0[ni], 32);
    ps1[ni] += __shfl_xor(ps1[ni], 16); ps1[ni] += __shfl_xor(ps1[ni], 32);
    ps2[ni] += __shfl_xor(ps2[ni], 16); ps2[ni] += __shfl_xor(ps2[ni], 32);
  }
  if (g4 == 0){
    #pragma unroll
    for (int ni=0;ni<8;++ni){
      int col = wn*128 + ni*16 + cl;
      atomicAdd(&S0[gb*M_ + col], ps0[ni]);
      atomicAdd(&S1[gb*M_ + col], ps1[ni]);
      atomicAdd(&S2[gb*M_ + col], ps2[ni]);
    }
  }
}

// ---------------- finalize role_value / role_var / role_cov -----------------
__global__ __launch_bounds__(256) void k_final(const float* __restrict__ S0,
                                               const float* __restrict__ S1,
                                               const float* __restrict__ S2,
                                               const float* __restrict__ supp,
                                               float* __restrict__ out,
                                               float* __restrict__ rvf){
  int i = blockIdx.x*256 + threadIdx.x;   // 4096
  int b = i >> 8;
  float s0 = S0[i], s1 = S1[i], s2 = S2[i];
  float cov = fmaxf(s0, 1e-6f);
  float rv = s1 / cov;
  float var = fmaxf((s2 - 2.f*rv*s1 + rv*rv*s0) / cov, 1e-4f);
  float rc = fmaxf(cov / supp[b], 0.05f);
  out[O_RVAL + i] = rv;
  out[O_RVAR + i] = var;
  out[O_RCOV + i] = rc;
  rvf[i] = rv;
}

// ---------------- prompt_role_fit = (attn . role_value) * mask --------------
__global__ __launch_bounds__(256) void k_fit(const float* __restrict__ attn,
                                             const float* __restrict__ rvf,
                                             const float* __restrict__ msk,
                                             float* __restrict__ out){
  int wid = threadIdx.x >> 6, lane = threadIdx.x & 63;
  int row = blockIdx.x*4 + wid;
  int b = row >> 12;
  float4 a = *(const float4*)(attn + (long)row*M_ + lane*4);
  float4 r = *(const float4*)(rvf + b*M_ + lane*4);
  float dot = a.x*r.x + a.y*r.y + a.z*r.z + a.w*r.w;
  #pragma unroll
  for (int d=1; d<64; d<<=1) dot += __shfl_xor(dot, d);
  if (lane == 0) out[O_FIT + row] = dot * clip01(msk[row]);
}

// ---------------- launcher --------------------------------------------------
extern "C" void kernel_launch(void* const* d_in, const int* in_sizes, int n_in,
                              void* d_out, int out_size, void* d_ws, size_t ws_size,
                              hipStream_t stream) {
  const int*   units = (const int*)d_in[0];
  const float* dur   = (const float*)d_in[1];
  const float* msk   = (const float*)d_in[2];
  const float* emb   = (const float*)d_in[3];
  const float* pw    = (const float*)d_in[4];
  const float* pb    = (const float*)d_in[5];
  const float* w1    = (const float*)d_in[6];
  const float* b1    = (const float*)d_in[7];
  const float* w2    = (const float*)d_in[8];
  const float* b2c   = (const float*)d_in[9];
  const float* lng   = (const float*)d_in[10];
  const float* lnb   = (const float*)d_in[11];
  const float* rk    = (const float*)d_in[12];
  float* out = (float*)d_out;
  char* ws = (char*)d_ws;

  // pick the largest batch-chunk C whose workspace fits ws_size
  const size_t chunkB = (size_t)TP_*D_*2;              // per-batch padded bf16 bytes
  const size_t tail = 3145728 + 262144 + 262144 + 49152 + 64 + 16384;
  int C = 16;
  while (C > 1 && (2*(size_t)C*chunkB + tail) > ws_size) C >>= 1;
  const int nch = 16 / C;
  const size_t hB = (size_t)C*chunkB;

  u16*   h0c     = (u16*)(ws);
  u16*   h1c     = (u16*)(ws + hB);
  u16*   wrp     = (u16*)(ws + 2*hB);                          // 3,145,728 B
  u16*   rkb     = (u16*)(ws + 2*hB + 3145728);                // 262,144 B
  float* resid_f = (float*)(ws + 2*hB + 3145728 + 262144);     // 262,144 B
  float* S0      = (float*)(ws + 2*hB + 3145728 + 262144 + 262144);
  float* S1      = S0 + 4096;
  float* S2      = S1 + 4096;
  float* supp_f  = S2 + 4096;
  float* rv_f    = supp_f + 16;

  int initN = 2*(C << 10) + 12288 + 128;
  k_init  <<<(initN + 255)/256, 256, 0, stream>>>(h0c, h1c, C, S0, out);
  k_repack<<<6656, 256, 0, stream>>>(w1, w2, rk, wrp, rkb);
  k_median<<<16,  1024, 0, stream>>>(dur, msk, out, supp_f, resid_f);
  for (int c = 0; c < nch; ++c){
    int b0 = c*C;
    k_embed<<<C*1024, 256, 0, stream>>>(units, dur, msk, emb, pw, pb, h0c, b0);
    k_conv <<<C*64,   256, 0, stream>>>(h0c, wrp,          b1,  h1c);
    k_conv <<<C*64,   256, 0, stream>>>(h1c, wrp + 786432, b2c, h0c);
    k_ln   <<<C*1024, 256, 0, stream>>>(h0c, lng, lnb, msk, b0);
    k_score<<<C*32,   256, 0, stream>>>(h0c, rkb, msk, resid_f, S0, S1, S2, out, b0);
  }
  k_final <<<16,    256, 0, stream>>>(S0, S1, S2, supp_f, out, rv_f);
  k_fit   <<<16384, 256, 0, stream>>>(out + O_ATTN, rv_f, msk, out);
}

// Round 5
// 537.195 us; speedup vs baseline: 1.5592x; 1.2662x over previous
//
#include <hip/hip_runtime.h>
#include <math.h>
#include <stdint.h>

#define B_  16
#define T_  4096
#define D_  512
#define M_  256
#define TP_ 4098   // T + 2 causal pad rows (granule-column-major padded hidden layout)

// output element offsets (float elements, concatenated in reference return order)
static constexpr long O_RATE = 0;          // [B,1]
static constexpr long O_ZOP  = 16;         // [B,8]
static constexpr long O_RVAL = 144;        // [B,M]
static constexpr long O_RVAR = 4240;       // [B,M]
static constexpr long O_RCOV = 8336;       // [B,M]
static constexpr long O_MASK = 12432;      // [B,T]
static constexpr long O_LOGD = 77968;      // [B,T]
static constexpr long O_RESID= 143504;     // [B,T]
static constexpr long O_ATTN = 209040;     // [B,T,M]
static constexpr long O_FIT  = 16986256;   // [B,T]

typedef unsigned short u16;
typedef unsigned int u32;
typedef __attribute__((ext_vector_type(8))) __bf16 bf16x8;
typedef __attribute__((ext_vector_type(4))) float fx4;

__device__ __forceinline__ float b2f(u16 u){ union{float f;uint32_t i;}v; v.i=((uint32_t)u)<<16; return v.f; }
__device__ __forceinline__ u16 f2b(float f){ union{float f;uint32_t i;}v; v.f=f; uint32_t r=v.i+0x7fffu+((v.i>>16)&1u); return (u16)(r>>16); }
__device__ __forceinline__ float clip01(float x){ return fminf(fmaxf(x, 0.f), 1.f); }
__device__ __forceinline__ float gelu_f(float x){ return 0.5f*x*(1.0f+erff(x*0.70710678118654752440f)); }

__device__ __forceinline__ void cp16(const u16* g, u16* l){
  __builtin_amdgcn_global_load_lds((__attribute__((address_space(1))) void*)g,
                                   (__attribute__((address_space(3))) void*)l, 16, 0, 0);
}

// hidden layout: granule(b,g,t) at ((b*64+g)*TP_ + t), 8 u16 each.

// ---------------- init: zero pads of h0 & hA, zero_operator -----------------
__global__ void k_init(u16* __restrict__ h0, u16* __restrict__ hA, int Cloc,
                       float* __restrict__ out){
  int i = blockIdx.x*256 + threadIdx.x;
  int nA = Cloc << 7;                       // h0 pad granules: C*64g*2t
  if (i < nA){
    int lb = i >> 7, r = i & 127, g = r >> 1, t = r & 1;
    *(uint4*)(h0 + ((long)(lb*64 + g)*TP_ + t)*8) = make_uint4(0,0,0,0);
  } else if (i < nA + 2048){
    int j = i - nA;
    int b = j >> 7, r = j & 127, g = r >> 1, t = r & 1;
    *(uint4*)(hA + ((long)(b*64 + g)*TP_ + t)*8) = make_uint4(0,0,0,0);
  } else if (i < nA + 2048 + 128){
    out[O_ZOP + (i - nA - 2048)] = 0.f;
  }
}

// ---- repack: conv weights -> pre-tiled bf16 [conv][tap][kt][g][row512];
//      role_key -> bf16 (gain-folded) pre-tiled [kt][g][row256]
__global__ void k_repack(const float* __restrict__ w1, const float* __restrict__ w2,
                         const float* __restrict__ rk, const float* __restrict__ lng,
                         u16* __restrict__ wrp2, u16* __restrict__ rkb){
  int i = blockIdx.x*256 + threadIdx.x;       // 1572864 + 131072
  if (i < 1572864){
    int gi = i >> 3, c7 = i & 7;
    int row = gi & 511;                 // out channel
    int g   = (gi >> 9) & 3;
    int kt  = (gi >> 11) & 15;
    int tg  = gi >> 15;                 // 0..5
    int conv = tg / 3, tap = tg % 3;
    int ic = kt*32 + g*8 + c7;
    const float* w = conv ? w2 : w1;
    wrp2[i] = f2b(w[(row*512 + ic)*3 + tap]);
  } else {
    int j = i - 1572864;
    int gi = j >> 3, c7 = j & 7;
    int n  = gi & 255;
    int g  = (gi >> 8) & 3;
    int kt = gi >> 10;
    int k  = kt*32 + g*8 + c7;
    rkb[j] = f2b(rk[n*512 + k] * lng[k]);
  }
}

// ---- GB[n] = sum_k g[k]*key[n,k]; BeB[n] = sum_k be[k]*key[n,k] ------------
__global__ __launch_bounds__(64) void k_gbb(const float* __restrict__ rk,
                                            const float* __restrict__ lng,
                                            const float* __restrict__ lnb,
                                            float* __restrict__ GB,
                                            float* __restrict__ BeB){
  int n = blockIdx.x, lane = threadIdx.x;
  float sg = 0.f, sb = 0.f;
  #pragma unroll
  for (int j = 0; j < 8; ++j){
    int k = lane*8 + j;
    float kv = rk[(long)n*512 + k];
    sg += lng[k]*kv; sb += lnb[k]*kv;
  }
  #pragma unroll
  for (int d=1; d<64; d<<=1){ sg += __shfl_xor(sg, d); sb += __shfl_xor(sb, d); }
  if (lane == 0){ GB[n] = sg; BeB[n] = sb; }
}

// ---------------- per-batch: mask/logdur outputs, exact lower median --------
__global__ __launch_bounds__(1024) void k_median(
    const float* __restrict__ dur, const float* __restrict__ msk,
    float* __restrict__ out, float* __restrict__ supp_f){
  __shared__ u32 keys[4096];
  __shared__ u32 hist[2048];
  __shared__ float sred[1024];
  __shared__ u32 selBin, selRank;
  __shared__ float sMed;
  const int tid = threadIdx.x;
  const int b = blockIdx.x;
  float msum = 0.f;
  for (int i = tid; i < 4096; i += 1024){
    int bt = (b << 12) + i;
    float m  = clip01(msk[bt]);
    float ld = logf(fmaxf(dur[bt], 1e-4f)) * m;
    out[O_MASK + bt] = m;
    out[O_LOGD + bt] = ld;
    u32 u = __float_as_uint(ld);
    u32 k = (u & 0x80000000u) ? ~u : (u | 0x80000000u);
    keys[i] = (m > 0.5f) ? k : 0xFFFFFFFFu;
    msum += m;
  }
  sred[tid] = msum;
  __syncthreads();
  for (int s = 512; s > 0; s >>= 1){
    if (tid < s) sred[tid] += sred[tid + s];
    __syncthreads();
  }
  float msumT = sred[0];
  int cnt = (int)(msumT + 0.5f);
  u32 prefix = 0;
  u32 r = (cnt > 0) ? (u32)((cnt - 1) >> 1) : 0u;
  if (cnt > 0){
    #pragma unroll
    for (int p = 0; p < 3; ++p){
      const int shift = (p==0) ? 21 : (p==1) ? 10 : 0;
      const int nb = (p==2) ? 1024 : 2048;
      const u32 himask = (p==0) ? 0u : (0xFFFFFFFFu << (shift + ((p==2)?10:11)));
      hist[tid] = 0u; hist[tid + 1024] = 0u;
      __syncthreads();
      for (int i = tid; i < 4096; i += 1024){
        u32 k = keys[i];
        if ((k & himask) == prefix)
          atomicAdd(&hist[(k >> shift) & (u32)(nb-1)], 1u);
      }
      __syncthreads();
      if (tid < 64){
        u32 lane = tid;
        u32 cum = 0;
        for (int chunk = 0; chunk < nb/64; ++chunk){
          u32 v = hist[chunk*64 + lane];
          u32 incl = v;
          #pragma unroll
          for (int d = 1; d < 64; d <<= 1){
            u32 o = __shfl_up(incl, d);
            if (lane >= (u32)d) incl += o;
          }
          u32 total = __shfl(incl, 63);
          if (r < cum + total){
            u32 excl = incl - v;
            bool hit = (r >= cum + excl) && (r < cum + excl + v);
            unsigned long long bal = __ballot(hit);
            int L = __ffsll((unsigned long long)bal) - 1;
            u32 exclL = __shfl(excl, L);
            if (lane == 0){ selBin = (u32)(chunk*64 + L); selRank = r - (cum + exclL); }
            break;
          }
          cum += total;
        }
      }
      __syncthreads();
      prefix |= (selBin << shift);
      r = selRank;
      __syncthreads();
    }
  }
  if (tid == 0){
    float med = 0.f;
    if (cnt > 0){
      u32 k = prefix;
      u32 u = (k & 0x80000000u) ? (k ^ 0x80000000u) : ~k;
      med = __uint_as_float(u);
    }
    out[O_RATE + b] = med;
    supp_f[b] = fmaxf(msumT, 1.0f);
    sMed = med;
  }
  __syncthreads();
  float med = sMed;
  for (int i = tid; i < 4096; i += 1024){
    int bt = (b << 12) + i;
    float m  = clip01(msk[bt]);
    float ld = logf(fmaxf(dur[bt], 1e-4f)) * m;
    out[O_RESID + bt] = (ld - med) * m;
  }
}

// ---------------- embedding + aux proj -> h0 [g][t] (coalesced writes) ------
__global__ __launch_bounds__(256) void k_embed(
    const int* __restrict__ units, const float* __restrict__ dur,
    const float* __restrict__ msk, const float* __restrict__ emb,
    const float* __restrict__ pw, const float* __restrict__ pb,
    u16* __restrict__ h0, int b0){
  int wid = threadIdx.x >> 6, lane = threadIdx.x & 63;
  int w = blockIdx.x*4 + wid;           // over C*64g*64tb
  int tb = w & 63, g = (w >> 6) & 63, lb = w >> 12;
  int t = tb*64 + lane;
  int bt = ((b0 + lb) << 12) + t;
  float m = clip01(msk[bt]);
  float ld = logf(fmaxf(dur[bt], 1e-4f)) * m;
  long u = units[bt];
  const float* er = emb + u*512 + g*8;
  float4 e0 = *(const float4*)er;
  float4 e1 = *(const float4*)(er + 4);
  float x[8] = {e0.x,e0.y,e0.z,e0.w,e1.x,e1.y,e1.z,e1.w};
  union { u16 s[8]; uint4 v; } o;
  #pragma unroll
  for (int j=0;j<8;++j)
    o.s[j] = f2b(x[j] + ld*pw[(g*8+j)*4] + pb[g*8+j]);
  *(uint4*)(h0 + ((long)(lb*64 + g)*TP_ + 2 + t)*8) = o.v;
}

// ---------------- causal conv (K=3) MFMA GEMM, 128x128 tile -----------------
// A in [g][t] layout (coalesced stage); B pre-tiled (coalesced stage).
// STATS: accumulate per-row sum/sumsq of gelu output (for fused LN).
template<int STATS>
__global__ __launch_bounds__(256, 4) void k_conv(const u16* __restrict__ hin,
                                                 const u16* __restrict__ wrp2c,
                                                 const float* __restrict__ bias,
                                                 u16* __restrict__ hout,
                                                 float* __restrict__ rsum,
                                                 float* __restrict__ rsumsq,
                                                 int statsBase){
  __shared__ __align__(16) u16 smem[16640];   // 544 A + 1536 B granules; epilogue reuse
  const int tid = threadIdx.x;
  const int lane = tid & 63, wid = tid >> 6;
  const int wm = wid >> 1, wn = wid & 1;
  const int nt = blockIdx.x & 3, mt = blockIdx.x >> 2;
  const int lb = mt >> 5, t0 = (mt & 31) << 7;
  const int n0 = nt << 7;
  const int g4 = lane >> 4, r16 = lane & 15;
  const int maxRow = (TP_ - 1) - t0;
  const long aG = (long)lb*64*TP_;

  fx4 acc[4][4];
  #pragma unroll
  for (int i=0;i<4;++i)
    #pragma unroll
    for (int j=0;j<4;++j){ acc[i][j][0]=0.f; acc[i][j][1]=0.f; acc[i][j][2]=0.f; acc[i][j][3]=0.f; }

  for (int kt = 0; kt < 16; ++kt){
    // stage A: 4 granule-cols x 136 t-rows, contiguous in global & LDS
    #pragma unroll
    for (int q = 0; q < 3; ++q){
      int s = q*256 + tid;
      if (s < 544){
        int gl = s / 136, row = s - gl*136;
        int rowc = min(row, maxRow);
        cp16(hin + (aG + (long)(kt*4 + gl)*TP_ + t0 + rowc)*8, &smem[s*8]);
      }
    }
    // stage B: [tap][g][row128] from pre-tiled weights, fully contiguous
    #pragma unroll
    for (int q = 0; q < 6; ++q){
      int s2 = q*256 + tid;
      int tap = s2 >> 9, g = (s2 >> 7) & 3, row = s2 & 127;
      cp16(wrp2c + ((long)((tap*16 + kt)*4 + g)*512 + n0 + row)*8, &smem[(544 + s2)*8]);
    }
    __syncthreads();
    #pragma unroll
    for (int tap = 0; tap < 3; ++tap){
      bf16x8 af[4], bf[4];
      #pragma unroll
      for (int mi=0;mi<4;++mi)
        af[mi] = *(const bf16x8*)&smem[(g4*136 + wm*64 + mi*16 + r16 + tap)*8];
      #pragma unroll
      for (int ni=0;ni<4;++ni)
        bf[ni] = *(const bf16x8*)&smem[(544 + tap*512 + g4*128 + wn*64 + ni*16 + r16)*8];
      #pragma unroll
      for (int mi=0;mi<4;++mi)
        #pragma unroll
        for (int ni=0;ni<4;++ni)
          acc[mi][ni] = __builtin_amdgcn_mfma_f32_16x16x32_bf16(af[mi], bf[ni], acc[mi][ni], 0,0,0);
    }
    __syncthreads();
  }
  // bias + gelu (+stats), then LDS transpose -> coalesced [g][t] stores
  const int cl = r16;
  float bv[4];
  #pragma unroll
  for (int ni=0;ni<4;++ni) bv[ni] = bias[n0 + wn*64 + ni*16 + cl];
  float vv[4][4][4];
  #pragma unroll
  for (int mi=0;mi<4;++mi)
    #pragma unroll
    for (int rg=0;rg<4;++rg){
      float sv = 0.f, sv2 = 0.f;
      #pragma unroll
      for (int ni=0;ni<4;++ni){
        float v = gelu_f(acc[mi][ni][rg] + bv[ni]);
        vv[mi][ni][rg] = v;
        if (STATS){ sv += v; sv2 += v*v; }
      }
      if (STATS){
        #pragma unroll
        for (int d=1; d<16; d<<=1){ sv += __shfl_xor(sv, d); sv2 += __shfl_xor(sv2, d); }
        if (cl == 0){
          int grow = statsBase + lb*4096 + t0 + wm*64 + mi*16 + g4*4 + rg;
          atomicAdd(&rsum[grow], sv);
          atomicAdd(&rsumsq[grow], sv2);
        }
      }
    }
  #pragma unroll
  for (int h = 0; h < 2; ++h){
    if (wm == h){
      #pragma unroll
      for (int mi=0;mi<4;++mi)
        #pragma unroll
        for (int ni=0;ni<4;++ni)
          #pragma unroll
          for (int rg=0;rg<4;++rg){
            int lr = mi*16 + g4*4 + rg;
            smem[lr*136 + wn*64 + ni*16 + cl] = f2b(vv[mi][ni][rg]);
          }
    }
    __syncthreads();
    #pragma unroll
    for (int it = 0; it < 4; ++it){
      int gc = it*4 + (tid >> 6), tr = tid & 63;
      long gran = aG + (long)(nt*16 + gc)*TP_ + 2 + t0 + h*64 + tr;
      *(uint4*)(hout + gran*8) = *(const uint4*)&smem[tr*136 + gc*8];
    }
    __syncthreads();
  }
}

// -------- score GEMM (LN fused as affine) + softmax + attn + S-reductions ---
__global__ __launch_bounds__(256, 2) void k_score(const u16* __restrict__ h,
                                                  const u16* __restrict__ rkb,
                                                  const float* __restrict__ msk,
                                                  const float* __restrict__ rsum,
                                                  const float* __restrict__ rsumsq,
                                                  const float* __restrict__ GB,
                                                  const float* __restrict__ BeB,
                                                  float* __restrict__ S0,
                                                  float* __restrict__ S1,
                                                  float* __restrict__ S2,
                                                  float* __restrict__ out, int b0){
  __shared__ __align__(16) u16 smem[12288];   // 512 A + 1024 B granules
  __shared__ float smax[128][2];
  __shared__ float ssum[128][2];
  const int tid = threadIdx.x;
  const int lane = tid & 63, wid = tid >> 6;
  const int wm = wid >> 1, wn = wid & 1;
  const int r0 = blockIdx.x << 7;
  const int lb = r0 >> 12, t0 = r0 & 4095;
  const int gb = b0 + lb;
  const long gRow0 = ((long)gb << 12) + t0;
  const long aG = (long)lb*64*TP_;
  const int g4 = lane >> 4, r16 = lane & 15;

  fx4 acc[4][8];
  #pragma unroll
  for (int i=0;i<4;++i)
    #pragma unroll
    for (int j=0;j<8;++j){ acc[i][j][0]=0.f; acc[i][j][1]=0.f; acc[i][j][2]=0.f; acc[i][j][3]=0.f; }

  for (int kt = 0; kt < 16; ++kt){
    #pragma unroll
    for (int q = 0; q < 2; ++q){
      int s = q*256 + tid;
      int gl = s >> 7, row = s & 127;
      cp16(h + (aG + (long)(kt*4 + gl)*TP_ + 2 + t0 + row)*8, &smem[s*8]);
    }
    #pragma unroll
    for (int q = 0; q < 4; ++q){
      int s2 = q*256 + tid;
      cp16(rkb + ((long)kt*1024 + s2)*8, &smem[(512 + s2)*8]);
    }
    __syncthreads();
    bf16x8 af[4], bf[8];
    #pragma unroll
    for (int mi=0;mi<4;++mi)
      af[mi] = *(const bf16x8*)&smem[(g4*128 + wm*64 + mi*16 + r16)*8];
    #pragma unroll
    for (int ni=0;ni<8;++ni)
      bf[ni] = *(const bf16x8*)&smem[(512 + g4*256 + wn*128 + ni*16 + r16)*8];
    #pragma unroll
    for (int mi=0;mi<4;++mi)
      #pragma unroll
      for (int ni=0;ni<8;++ni)
        acc[mi][ni] = __builtin_amdgcn_mfma_f32_16x16x32_bf16(af[mi], bf[ni], acc[mi][ni], 0,0,0);
    __syncthreads();
  }
  const float SCALE = 0.044194173824159216f;   // 1/sqrt(512)
  const int cl = r16;
  float gbv[8], bbv[8];
  #pragma unroll
  for (int ni=0;ni<8;++ni){
    int col = wn*128 + ni*16 + cl;
    gbv[ni] = GB[col]; bbv[ni] = BeB[col];
  }
  float gmx[4][4];
  #pragma unroll
  for (int mi=0;mi<4;++mi)
    #pragma unroll
    for (int rg=0;rg<4;++rg){
      int row = wm*64 + mi*16 + g4*4 + rg;
      long gRow = gRow0 + row;
      float mk = clip01(msk[gRow]);
      float mu = rsum[gRow] * (1.f/512.f);
      float var = rsumsq[gRow] * (1.f/512.f) - mu*mu;
      float inv = rsqrtf(var + 1e-5f);
      float mx = -1e30f;
      #pragma unroll
      for (int ni=0;ni<8;++ni){
        float s = mk * SCALE * (inv*(acc[mi][ni][rg] - mu*gbv[ni]) + bbv[ni]);
        acc[mi][ni][rg] = s;
        mx = fmaxf(mx, s);
      }
      #pragma unroll
      for (int d=1; d<16; d<<=1) mx = fmaxf(mx, __shfl_xor(mx, d));
      if (cl == 0) smax[row][wn] = mx;
    }
  __syncthreads();
  #pragma unroll
  for (int mi=0;mi<4;++mi)
    #pragma unroll
    for (int rg=0;rg<4;++rg){
      int row = wm*64 + mi*16 + g4*4 + rg;
      gmx[mi][rg] = fmaxf(smax[row][0], smax[row][1]);
    }
  #pragma unroll
  for (int mi=0;mi<4;++mi)
    #pragma unroll
    for (int rg=0;rg<4;++rg){
      float s = 0.f;
      #pragma unroll
      for (int ni=0;ni<8;++ni){
        float e = expf(acc[mi][ni][rg] - gmx[mi][rg]);
        acc[mi][ni][rg] = e;
        s += e;
      }
      #pragma unroll
      for (int d=1; d<16; d<<=1) s += __shfl_xor(s, d);
      if (cl == 0) ssum[wm*64 + mi*16 + g4*4 + rg][wn] = s;
    }
  __syncthreads();
  float ps0[8], ps1[8], ps2[8];
  #pragma unroll
  for (int ni=0;ni<8;++ni){ ps0[ni]=0.f; ps1[ni]=0.f; ps2[ni]=0.f; }
  #pragma unroll
  for (int mi=0;mi<4;++mi)
    #pragma unroll
    for (int rg=0;rg<4;++rg){
      int row = wm*64 + mi*16 + g4*4 + rg;
      long gRow = gRow0 + row;
      float tot = ssum[row][0] + ssum[row][1];
      float mk = clip01(msk[gRow]);
      float f = mk / tot;
      float rr = out[O_RESID + gRow];
      #pragma unroll
      for (int ni=0;ni<8;++ni){
        float a = acc[mi][ni][rg] * f;
        out[O_ATTN + gRow*M_ + wn*128 + ni*16 + cl] = a;
        ps0[ni] += a; ps1[ni] += a*rr; ps2[ni] += a*rr*rr;
      }
    }
  #pragma unroll
  for (int ni=0;ni<8;++ni){
    ps0[ni] += __shfl_xor(ps0[ni], 16); ps0[ni] += __shfl_xor(ps0[ni], 32);
    ps1[ni] += __shfl_xor(ps1[ni], 16); ps1[ni] += __shfl_xor(ps1[ni], 32);
    ps2[ni] += __shfl_xor(ps2[ni], 16); ps2[ni] += __shfl_xor(ps2[ni], 32);
  }
  if (g4 == 0){
    #pragma unroll
    for (int ni=0;ni<8;++ni){
      int col = wn*128 + ni*16 + cl;
      atomicAdd(&S0[gb*M_ + col], ps0[ni]);
      atomicAdd(&S1[gb*M_ + col], ps1[ni]);
      atomicAdd(&S2[gb*M_ + col], ps2[ni]);
    }
  }
}

// ---------------- finalize role_value / role_var / role_cov -----------------
__global__ __launch_bounds__(256) void k_final(const float* __restrict__ S0,
                                               const float* __restrict__ S1,
                                               const float* __restrict__ S2,
                                               const float* __restrict__ supp,
                                               float* __restrict__ out,
                                               float* __restrict__ rvf){
  int i = blockIdx.x*256 + threadIdx.x;   // 4096
  int b = i >> 8;
  float s0 = S0[i], s1 = S1[i], s2 = S2[i];
  float cov = fmaxf(s0, 1e-6f);
  float rv = s1 / cov;
  float var = fmaxf((s2 - 2.f*rv*s1 + rv*rv*s0) / cov, 1e-4f);
  float rc = fmaxf(cov / supp[b], 0.05f);
  out[O_RVAL + i] = rv;
  out[O_RVAR + i] = var;
  out[O_RCOV + i] = rc;
  rvf[i] = rv;
}

// ---------------- prompt_role_fit = (attn . role_value) * mask --------------
__global__ __launch_bounds__(256) void k_fit(const float* __restrict__ attn,
                                             const float* __restrict__ rvf,
                                             const float* __restrict__ msk,
                                             float* __restrict__ out){
  int wid = threadIdx.x >> 6, lane = threadIdx.x & 63;
  int row = blockIdx.x*4 + wid;
  int b = row >> 12;
  float4 a = *(const float4*)(attn + (long)row*M_ + lane*4);
  float4 r = *(const float4*)(rvf + b*M_ + lane*4);
  float dot = a.x*r.x + a.y*r.y + a.z*r.z + a.w*r.w;
  #pragma unroll
  for (int d=1; d<64; d<<=1) dot += __shfl_xor(dot, d);
  if (lane == 0) out[O_FIT + row] = dot * clip01(msk[row]);
}

// ---------------- launcher --------------------------------------------------
extern "C" void kernel_launch(void* const* d_in, const int* in_sizes, int n_in,
                              void* d_out, int out_size, void* d_ws, size_t ws_size,
                              hipStream_t stream) {
  const int*   units = (const int*)d_in[0];
  const float* dur   = (const float*)d_in[1];
  const float* msk   = (const float*)d_in[2];
  const float* emb   = (const float*)d_in[3];
  const float* pw    = (const float*)d_in[4];
  const float* pb    = (const float*)d_in[5];
  const float* w1    = (const float*)d_in[6];
  const float* b1    = (const float*)d_in[7];
  const float* w2    = (const float*)d_in[8];
  const float* b2c   = (const float*)d_in[9];
  const float* lng   = (const float*)d_in[10];
  const float* lnb   = (const float*)d_in[11];
  const float* rk    = (const float*)d_in[12];
  float* out = (float*)d_out;
  char* ws = (char*)d_ws;

  // conv1 output lives in the (dead-until-k_score) attn+fit region of d_out
  u16* hA = (u16*)(out + O_ATTN);

  const size_t perB = (size_t)64*TP_*16;               // 4,196,352 B per batch
  const size_t tail = 3145728 + 262144 + 1024 + 1024 + 64 + 16384 + 49152 + 262144 + 262144;
  int C = 16;
  while (C > 1 && ((size_t)C*perB + tail) > ws_size) C >>= 1;
  const int nch = 16 / C;

  char* p = ws;
  u16*   h0    = (u16*)p;            p += (size_t)C*perB;
  u16*   wrp2  = (u16*)p;            p += 3145728;
  u16*   rkb   = (u16*)p;            p += 262144;
  float* GB    = (float*)p;          p += 1024;
  float* BeB   = (float*)p;          p += 1024;
  float* supp_f= (float*)p;          p += 64;
  float* rv_f  = (float*)p;          p += 16384;
  float* S0    = (float*)p;          p += 49152;  // S0,S1,S2
  float* S1    = S0 + 4096;
  float* S2    = S1 + 4096;
  float* rsum  = (float*)p;          p += 262144;
  float* rsumsq= (float*)p;          p += 262144;

  hipMemsetAsync(S0, 0, 49152 + 262144 + 262144, stream);
  int initN = (C << 7) + 2048 + 128;
  k_init  <<<(initN + 255)/256, 256, 0, stream>>>(h0, hA, C, out);
  k_repack<<<6656, 256, 0, stream>>>(w1, w2, rk, lng, wrp2, rkb);
  k_gbb   <<<256,   64, 0, stream>>>(rk, lng, lnb, GB, BeB);
  k_median<<<16,  1024, 0, stream>>>(dur, msk, out, supp_f);
  for (int c = 0; c < nch; ++c){
    int b0 = c*C;
    u16* hAc = hA + (size_t)b0*64*TP_*8;
    k_embed  <<<C*1024, 256, 0, stream>>>(units, dur, msk, emb, pw, pb, h0, b0);
    k_conv<0><<<C*128,  256, 0, stream>>>(h0,  wrp2,           b1,  hAc, rsum, rsumsq, 0);
    k_conv<1><<<C*128,  256, 0, stream>>>(hAc, wrp2 + 786432,  b2c, h0,  rsum, rsumsq, b0*4096);
    k_score  <<<C*32,   256, 0, stream>>>(h0, rkb, msk, rsum, rsumsq, GB, BeB, S0, S1, S2, out, b0);
  }
  k_final <<<16,    256, 0, stream>>>(S0, S1, S2, supp_f, out, rv_f);
  k_fit   <<<16384, 256, 0, stream>>>(out + O_ATTN, rv_f, msk, out);
}